// Round 1
// baseline (919.383 us; speedup 1.0000x reference)
//
#include <hip/hip_runtime.h>
#include <cstdint>

#define S_LEN 2048
#define D_DIM 4096
#define NHEAD 32
#define NKVH  8
#define HDIM  128
#define NQKV  6144

typedef __bf16 bf16x8 __attribute__((ext_vector_type(8)));
typedef float floatx4 __attribute__((ext_vector_type(4)));
typedef unsigned short u16;
typedef unsigned int u32;

__device__ __forceinline__ u16 f2bf(float f) {
  u32 u = __builtin_bit_cast(u32, f);
  u += 0x7fffu + ((u >> 16) & 1u);
  return (u16)(u >> 16);
}
__device__ __forceinline__ float bf2f(u16 h) {
  u32 u = ((u32)h) << 16;
  return __builtin_bit_cast(float, u);
}

// async global->LDS, 16B per lane; LDS dest = wave-uniform base + lane*16
__device__ __forceinline__ void gll16(const void* g, const void* l) {
  __builtin_amdgcn_global_load_lds(
      (const __attribute__((address_space(1))) u32*)(unsigned long long)(uintptr_t)g,
      (__attribute__((address_space(3))) u32*)(u32)(uintptr_t)l, 16, 0, 0);
}

// ---------------- prep kernels ----------------

__global__ __launch_bounds__(256) void cast_f32_bf16(const float* __restrict__ src,
                                                     u16* __restrict__ dst, int n) {
  int i = (blockIdx.x * 256 + threadIdx.x) * 4;
  if (i >= n) return;
  float4 v = *(const float4*)(src + i);
  u32 lo = (u32)f2bf(v.x) | ((u32)f2bf(v.y) << 16);
  u32 hi = (u32)f2bf(v.z) | ((u32)f2bf(v.w) << 16);
  *(uint2*)(dst + i) = make_uint2(lo, hi);
}

// src [K,N] f32 -> dst [N,K] bf16 (64x64 tiles)
__global__ __launch_bounds__(256) void transpose_cast(const float* __restrict__ src,
                                                      u16* __restrict__ dst, int K, int N) {
  __shared__ float tile[64][65];
  int k0 = blockIdx.x * 64, n0 = blockIdx.y * 64;
  int t = threadIdx.x, c = t & 63, r0 = t >> 6;
#pragma unroll
  for (int p = 0; p < 16; ++p) {
    int r = r0 + p * 4;
    tile[r][c] = src[(size_t)(k0 + r) * N + n0 + c];
  }
  __syncthreads();
#pragma unroll
  for (int p = 0; p < 16; ++p) {
    int rr = r0 + p * 4;  // n-local
    dst[(size_t)(n0 + rr) * K + k0 + c] = f2bf(tile[c][rr]);
  }
}

// extract V from qkv [S][6144] and transpose per kv-head -> vt [NKVH][HDIM][S]
__global__ __launch_bounds__(256) void vt_kernel(const u16* __restrict__ qkv,
                                                 u16* __restrict__ vt) {
  __shared__ u16 tile[64][65];
  int s0 = blockIdx.x * 64, d0 = blockIdx.y * 64, hk = blockIdx.z;
  int t = threadIdx.x, c = t & 63, r0 = t >> 6;
#pragma unroll
  for (int p = 0; p < 16; ++p) {
    int r = r0 + p * 4;  // s-local
    tile[r][c] = qkv[(size_t)(s0 + r) * NQKV + 5120 + hk * HDIM + d0 + c];
  }
  __syncthreads();
#pragma unroll
  for (int p = 0; p < 16; ++p) {
    int rr = r0 + p * 4;  // d-local
    vt[((size_t)hk * HDIM + d0 + rr) * S_LEN + s0 + c] = tile[c][rr];
  }
}

// in-place RoPE on q (heads 0..31) and k (heads 32..39) of qkv [S][6144]
__global__ __launch_bounds__(256) void rope_kernel(u16* __restrict__ qkv) {
  int s = blockIdx.x;
  int sub = threadIdx.x >> 6;
  int i = threadIdx.x & 63;  // pair index, dims (2i, 2i+1)
  int hh = blockIdx.y * 4 + sub;
  int colbase = (hh < NHEAD) ? hh * HDIM : D_DIM + (hh - NHEAD) * HDIM;
  u32* p = (u32*)(qkv + (size_t)s * NQKV + colbase) + i;
  u32 pr = *p;
  float x0 = bf2f((u16)(pr & 0xffffu));
  float x1 = bf2f((u16)(pr >> 16));
  // inv_freq = 500000^(-(2i)/128);  ln(500000) = 13.122363377404328
  float invf = expf(-(float)(2 * i) * (13.122363377404328f / 128.0f));
  float ang = (float)s * invf;
  float cs = cosf(ang), sn = sinf(ang);
  float o0 = x0 * cs - x1 * sn;
  float o1 = x0 * sn + x1 * cs;
  *p = (u32)f2bf(o0) | ((u32)f2bf(o1) << 16);
}

// ---------------- GEMM: C[M,N] = A[M,K] * Bt[N,K]^T  (bf16 in, bf16/f32 out) ----------------

template <bool BF16_OUT>
__global__ __launch_bounds__(256) void gemm_bt(const u16* __restrict__ A,
                                               const u16* __restrict__ Bt,
                                               void* __restrict__ Cout,
                                               int M, int N, int K) {
  __shared__ u16 As[128 * 32];
  __shared__ u16 Bs[128 * 32];
  const int tid = threadIdx.x;
  const int w = tid >> 6, lane = tid & 63;
  const int quad = lane >> 4, l15 = lane & 15;
  const int m0 = blockIdx.y * 128, n0 = blockIdx.x * 128;
  const int wm = (w & 1) * 64, wn = (w >> 1) * 64;
  floatx4 acc[4][4];
#pragma unroll
  for (int mi = 0; mi < 4; ++mi)
#pragma unroll
    for (int ni = 0; ni < 4; ++ni)
#pragma unroll
      for (int j = 0; j < 4; ++j) acc[mi][ni][j] = 0.0f;

  const int srow = w * 32 + (lane >> 2);  // staging row (this wave: +0, +16)
  const int kcol = (lane & 3) * 8;

  for (int k0 = 0; k0 < K; k0 += 32) {
#pragma unroll
    for (int i = 0; i < 2; ++i) {
      gll16(A + (size_t)(m0 + srow + i * 16) * K + k0 + kcol,
            As + (w * 32 + i * 16) * 32);
      gll16(Bt + (size_t)(n0 + srow + i * 16) * K + k0 + kcol,
            Bs + (w * 32 + i * 16) * 32);
    }
    __syncthreads();
    bf16x8 a[4], b[4];
#pragma unroll
    for (int mi = 0; mi < 4; ++mi)
      a[mi] = *(const bf16x8*)(As + (wm + mi * 16 + l15) * 32 + quad * 8);
#pragma unroll
    for (int ni = 0; ni < 4; ++ni)
      b[ni] = *(const bf16x8*)(Bs + (wn + ni * 16 + l15) * 32 + quad * 8);
#pragma unroll
    for (int mi = 0; mi < 4; ++mi)
#pragma unroll
      for (int ni = 0; ni < 4; ++ni)
        acc[mi][ni] = __builtin_amdgcn_mfma_f32_16x16x32_bf16(a[mi], b[ni], acc[mi][ni], 0, 0, 0);
    __syncthreads();
  }
#pragma unroll
  for (int mi = 0; mi < 4; ++mi)
#pragma unroll
    for (int ni = 0; ni < 4; ++ni) {
      int row = m0 + wm + mi * 16 + quad * 4;
      int col = n0 + wn + ni * 16 + l15;
#pragma unroll
      for (int j = 0; j < 4; ++j) {
        if (BF16_OUT)
          ((u16*)Cout)[(size_t)(row + j) * N + col] = f2bf(acc[mi][ni][j]);
        else
          ((float*)Cout)[(size_t)(row + j) * N + col] = acc[mi][ni][j];
      }
    }
}

// ---------------- flash attention ----------------
// grid (S/64, NHEAD); 4 waves, each owns 16 q rows. K/V frags straight from global (L2).
__global__ __launch_bounds__(256) void attn_kernel(const u16* __restrict__ qkv,
                                                   const u16* __restrict__ vt,
                                                   u16* __restrict__ attn_o) {
  __shared__ u16 plds[4][16 * 40];  // per-wave P transform buffer, stride 40
  const int tid = threadIdx.x, w = tid >> 6, lane = tid & 63;
  const int quad = lane >> 4, l15 = lane & 15;
  const int h = blockIdx.y, hk = h >> 2;
  const int qb = blockIdx.x * 64 + w * 16;
  const float scale = 0.08838834764831845f;  // 1/sqrt(128)

  bf16x8 qa[4];
  {
    const u16* qp = qkv + (size_t)(qb + l15) * NQKV + h * HDIM + quad * 8;
#pragma unroll
    for (int c = 0; c < 4; ++c) qa[c] = *(const bf16x8*)(qp + c * 32);
  }
  floatx4 o[8];
#pragma unroll
  for (int nf = 0; nf < 8; ++nf)
#pragma unroll
    for (int j = 0; j < 4; ++j) o[nf][j] = 0.0f;
  float mrow[4], lrow[4];
#pragma unroll
  for (int j = 0; j < 4; ++j) { mrow[j] = -1e30f; lrow[j] = 0.0f; }

  const int nkt = ((qb + 15) >> 5) + 1;
  const u16* kp = qkv + D_DIM + hk * HDIM + quad * 8;
  const u16* vp = vt + ((size_t)hk * HDIM + l15) * S_LEN + quad * 8;

  for (int kt = 0; kt < nkt; ++kt) {
    const int kb = kt * 32;
    floatx4 s0, s1;
#pragma unroll
    for (int j = 0; j < 4; ++j) { s0[j] = 0.0f; s1[j] = 0.0f; }
#pragma unroll
    for (int c = 0; c < 4; ++c) {
      bf16x8 k0f = *(const bf16x8*)(kp + (size_t)(kb + l15) * NQKV + c * 32);
      bf16x8 k1f = *(const bf16x8*)(kp + (size_t)(kb + 16 + l15) * NQKV + c * 32);
      s0 = __builtin_amdgcn_mfma_f32_16x16x32_bf16(qa[c], k0f, s0, 0, 0, 0);
      s1 = __builtin_amdgcn_mfma_f32_16x16x32_bf16(qa[c], k1f, s1, 0, 0, 0);
    }
    const int col0 = kb + l15, col1 = col0 + 16;
    const int rowg = qb + quad * 4;
    float al[4];
#pragma unroll
    for (int j = 0; j < 4; ++j) {
      float v0 = s0[j] * scale; if (col0 > rowg + j) v0 = -1e30f;
      float v1 = s1[j] * scale; if (col1 > rowg + j) v1 = -1e30f;
      float mj = fmaxf(v0, v1);
#pragma unroll
      for (int off = 1; off < 16; off <<= 1) mj = fmaxf(mj, __shfl_xor(mj, off, 64));
      float mn = fmaxf(mrow[j], mj);
      float a_ = __expf(mrow[j] - mn);
      mrow[j] = mn;
      float p0 = __expf(v0 - mn), p1 = __expf(v1 - mn);
      float sj = p0 + p1;
#pragma unroll
      for (int off = 1; off < 16; off <<= 1) sj += __shfl_xor(sj, off, 64);
      lrow[j] = lrow[j] * a_ + sj;
      al[j] = a_;
      plds[w][(quad * 4 + j) * 40 + l15] = f2bf(p0);
      plds[w][(quad * 4 + j) * 40 + 16 + l15] = f2bf(p1);
    }
#pragma unroll
    for (int nf = 0; nf < 8; ++nf)
#pragma unroll
      for (int j = 0; j < 4; ++j) o[nf][j] *= al[j];
    bf16x8 pa = *(const bf16x8*)(&plds[w][l15 * 40 + quad * 8]);
#pragma unroll
    for (int nf = 0; nf < 8; ++nf) {
      bf16x8 vb = *(const bf16x8*)(vp + (size_t)nf * 16 * S_LEN + kb);
      o[nf] = __builtin_amdgcn_mfma_f32_16x16x32_bf16(pa, vb, o[nf], 0, 0, 0);
    }
  }
  float rl[4];
#pragma unroll
  for (int j = 0; j < 4; ++j) rl[j] = 1.0f / lrow[j];
#pragma unroll
  for (int nf = 0; nf < 8; ++nf)
#pragma unroll
    for (int j = 0; j < 4; ++j) {
      int row = qb + quad * 4 + j;
      int col = h * HDIM + nf * 16 + l15;
      attn_o[(size_t)row * D_DIM + col] = f2bf(o[nf][j] * rl[j]);
    }
}

// ---------------- launcher ----------------

extern "C" void kernel_launch(void* const* d_in, const int* in_sizes, int n_in,
                              void* d_out, int out_size, void* d_ws, size_t ws_size,
                              hipStream_t stream) {
  const float* x  = (const float*)d_in[0];
  const float* Wq = (const float*)d_in[1];
  const float* Wk = (const float*)d_in[2];
  const float* Wv = (const float*)d_in[3];
  const float* Wo = (const float*)d_in[4];
  float* out = (float*)d_out;
  char* ws = (char*)d_ws;
  const size_t MB = 1024 * 1024;
  u16* x_bf   = (u16*)(ws);              // 16 MB
  u16* wqkvT  = (u16*)(ws + 16 * MB);    // 48 MB  [6144][4096] bf16
  u16* woT    = (u16*)(ws + 64 * MB);    // 32 MB  [4096][4096] bf16
  u16* qkv    = (u16*)(ws + 96 * MB);    // 24 MB  [2048][6144] bf16
  u16* vt     = (u16*)(ws + 120 * MB);   //  4 MB  [8][128][2048] bf16
  u16* attn_o = (u16*)(ws + 124 * MB);   // 16 MB  [2048][4096] bf16

  // 1. cast x
  cast_f32_bf16<<<8192, 256, 0, stream>>>(x, x_bf, S_LEN * D_DIM);
  // 2. cast+transpose weights into B^T layouts
  transpose_cast<<<dim3(64, 64), 256, 0, stream>>>(Wq, wqkvT, D_DIM, 4096);
  transpose_cast<<<dim3(64, 16), 256, 0, stream>>>(Wk, wqkvT + (size_t)4096 * D_DIM, D_DIM, 1024);
  transpose_cast<<<dim3(64, 16), 256, 0, stream>>>(Wv, wqkvT + (size_t)5120 * D_DIM, D_DIM, 1024);
  transpose_cast<<<dim3(64, 64), 256, 0, stream>>>(Wo, woT, D_DIM, D_DIM);
  // 3. fused QKV projection
  gemm_bt<true><<<dim3(48, 16), 256, 0, stream>>>(x_bf, wqkvT, qkv, S_LEN, NQKV, D_DIM);
  // 4. RoPE on q,k
  rope_kernel<<<dim3(S_LEN, 10), 256, 0, stream>>>(qkv);
  // 5. V transpose
  vt_kernel<<<dim3(32, 2, 8), 256, 0, stream>>>(qkv, vt);
  // 6. flash attention
  attn_kernel<<<dim3(S_LEN / 64, NHEAD), 256, 0, stream>>>(qkv, vt, attn_o);
  // 7. output projection (fp32 out)
  gemm_bt<false><<<dim3(32, 16), 256, 0, stream>>>(attn_o, woT, out, S_LEN, D_DIM, D_DIM);
}

// Round 2
// 652.822 us; speedup vs baseline: 1.4083x; 1.4083x over previous
//
#include <hip/hip_runtime.h>
#include <cstdint>

#define S_LEN 2048
#define D_DIM 4096
#define NHEAD 32
#define NKVH  8
#define HDIM  128
#define NQKV  6144

typedef __bf16 bf16x8 __attribute__((ext_vector_type(8)));
typedef float floatx4 __attribute__((ext_vector_type(4)));
typedef unsigned short u16;
typedef unsigned int u32;

__device__ __forceinline__ u16 f2bf(float f) {
  u32 u = __builtin_bit_cast(u32, f);
  u += 0x7fffu + ((u >> 16) & 1u);
  return (u16)(u >> 16);
}
__device__ __forceinline__ float bf2f(u16 h) {
  u32 u = ((u32)h) << 16;
  return __builtin_bit_cast(float, u);
}

// async global->LDS, 16B per lane; LDS dest = wave-uniform base + lane*16
__device__ __forceinline__ void gll16(const void* g, const void* l) {
  __builtin_amdgcn_global_load_lds(
      (const __attribute__((address_space(1))) u32*)(unsigned long long)(uintptr_t)g,
      (__attribute__((address_space(3))) u32*)(u32)(uintptr_t)l, 16, 0, 0);
}

// ---------------- prep kernels ----------------

__global__ __launch_bounds__(256) void cast_f32_bf16(const float* __restrict__ src,
                                                     u16* __restrict__ dst, int n) {
  int i = (blockIdx.x * 256 + threadIdx.x) * 4;
  if (i >= n) return;
  float4 v = *(const float4*)(src + i);
  u32 lo = (u32)f2bf(v.x) | ((u32)f2bf(v.y) << 16);
  u32 hi = (u32)f2bf(v.z) | ((u32)f2bf(v.w) << 16);
  *(uint2*)(dst + i) = make_uint2(lo, hi);
}

// src [K,N] f32 -> dst [N,K] bf16 (64x64 tiles)
__global__ __launch_bounds__(256) void transpose_cast(const float* __restrict__ src,
                                                      u16* __restrict__ dst, int K, int N) {
  __shared__ float tile[64][65];
  int k0 = blockIdx.x * 64, n0 = blockIdx.y * 64;
  int t = threadIdx.x, c = t & 63, r0 = t >> 6;
#pragma unroll
  for (int p = 0; p < 16; ++p) {
    int r = r0 + p * 4;
    tile[r][c] = src[(size_t)(k0 + r) * N + n0 + c];
  }
  __syncthreads();
#pragma unroll
  for (int p = 0; p < 16; ++p) {
    int rr = r0 + p * 4;  // n-local
    dst[(size_t)(n0 + rr) * K + k0 + c] = f2bf(tile[c][rr]);
  }
}

// extract V from qkv [S][6144] and transpose per kv-head -> vt [NKVH][HDIM][S]
__global__ __launch_bounds__(256) void vt_kernel(const u16* __restrict__ qkv,
                                                 u16* __restrict__ vt) {
  __shared__ u16 tile[64][65];
  int s0 = blockIdx.x * 64, d0 = blockIdx.y * 64, hk = blockIdx.z;
  int t = threadIdx.x, c = t & 63, r0 = t >> 6;
#pragma unroll
  for (int p = 0; p < 16; ++p) {
    int r = r0 + p * 4;  // s-local
    tile[r][c] = qkv[(size_t)(s0 + r) * NQKV + 5120 + hk * HDIM + d0 + c];
  }
  __syncthreads();
#pragma unroll
  for (int p = 0; p < 16; ++p) {
    int rr = r0 + p * 4;  // d-local
    vt[((size_t)hk * HDIM + d0 + rr) * S_LEN + s0 + c] = tile[c][rr];
  }
}

// in-place RoPE on q (heads 0..31) and k (heads 32..39) of qkv [S][6144]
__global__ __launch_bounds__(256) void rope_kernel(u16* __restrict__ qkv) {
  int s = blockIdx.x;
  int sub = threadIdx.x >> 6;
  int i = threadIdx.x & 63;  // pair index, dims (2i, 2i+1)
  int hh = blockIdx.y * 4 + sub;
  int colbase = (hh < NHEAD) ? hh * HDIM : D_DIM + (hh - NHEAD) * HDIM;
  u32* p = (u32*)(qkv + (size_t)s * NQKV + colbase) + i;
  u32 pr = *p;
  float x0 = bf2f((u16)(pr & 0xffffu));
  float x1 = bf2f((u16)(pr >> 16));
  float invf = expf(-(float)(2 * i) * (13.122363377404328f / 128.0f));
  float ang = (float)s * invf;
  float cs = cosf(ang), sn = sinf(ang);
  float o0 = x0 * cs - x1 * sn;
  float o1 = x0 * sn + x1 * cs;
  *p = (u32)f2bf(o0) | ((u32)f2bf(o1) << 16);
}

// ---------------- GEMM: C[M,N] = A[M,K] * Bt[N,K]^T ----------------

template <bool BF16_OUT>
__global__ __launch_bounds__(256) void gemm_bt(const u16* __restrict__ A,
                                               const u16* __restrict__ Bt,
                                               void* __restrict__ Cout,
                                               int M, int N, int K) {
  __shared__ u16 As[128 * 32];
  __shared__ u16 Bs[128 * 32];
  const int tid = threadIdx.x;
  const int w = tid >> 6, lane = tid & 63;
  const int quad = lane >> 4, l15 = lane & 15;
  const int m0 = blockIdx.y * 128, n0 = blockIdx.x * 128;
  const int wm = (w & 1) * 64, wn = (w >> 1) * 64;
  floatx4 acc[4][4];
#pragma unroll
  for (int mi = 0; mi < 4; ++mi)
#pragma unroll
    for (int ni = 0; ni < 4; ++ni)
#pragma unroll
      for (int j = 0; j < 4; ++j) acc[mi][ni][j] = 0.0f;

  const int srow = w * 32 + (lane >> 2);
  const int kcol = (lane & 3) * 8;

  for (int k0 = 0; k0 < K; k0 += 32) {
#pragma unroll
    for (int i = 0; i < 2; ++i) {
      gll16(A + (size_t)(m0 + srow + i * 16) * K + k0 + kcol,
            As + (w * 32 + i * 16) * 32);
      gll16(Bt + (size_t)(n0 + srow + i * 16) * K + k0 + kcol,
            Bs + (w * 32 + i * 16) * 32);
    }
    __syncthreads();
    bf16x8 a[4], b[4];
#pragma unroll
    for (int mi = 0; mi < 4; ++mi)
      a[mi] = *(const bf16x8*)(As + (wm + mi * 16 + l15) * 32 + quad * 8);
#pragma unroll
    for (int ni = 0; ni < 4; ++ni)
      b[ni] = *(const bf16x8*)(Bs + (wn + ni * 16 + l15) * 32 + quad * 8);
#pragma unroll
    for (int mi = 0; mi < 4; ++mi)
#pragma unroll
      for (int ni = 0; ni < 4; ++ni)
        acc[mi][ni] = __builtin_amdgcn_mfma_f32_16x16x32_bf16(a[mi], b[ni], acc[mi][ni], 0, 0, 0);
    __syncthreads();
  }
#pragma unroll
  for (int mi = 0; mi < 4; ++mi)
#pragma unroll
    for (int ni = 0; ni < 4; ++ni) {
      int row = m0 + wm + mi * 16 + quad * 4;
      int col = n0 + wn + ni * 16 + l15;
#pragma unroll
      for (int j = 0; j < 4; ++j) {
        if (BF16_OUT)
          ((u16*)Cout)[(size_t)(row + j) * N + col] = f2bf(acc[mi][ni][j]);
        else
          ((float*)Cout)[(size_t)(row + j) * N + col] = acc[mi][ni][j];
      }
    }
}

// ---------------- flash attention, LDS-staged ----------------
// grid (S/128, NHEAD); 4 waves, each owns 32 q rows (2 m-frags).
// K tile (64 keys x 128) and V^T tile (128 hd x 64 keys) staged in LDS per block.
__global__ __launch_bounds__(256) void attn_kernel(const u16* __restrict__ qkv,
                                                   const u16* __restrict__ vt,
                                                   u16* __restrict__ attn_o) {
  __shared__ u16 Ks[4][64 * 32];   // [k-chunk c][key][32 hd]    16 KB
  __shared__ u16 Vs[2][128 * 32];  // [key-chunk c][hd][32 keys] 16 KB
  __shared__ u16 Ps[4][16 * 72];   // per-wave P transform, stride 72
  const int tid = threadIdx.x, w = tid >> 6, lane = tid & 63;
  const int quad = lane >> 4, l15 = lane & 15;
  const int h = blockIdx.y, hk = h >> 2;
  const int bx = gridDim.x - 1 - blockIdx.x;  // heavy blocks first
  const int qb = bx * 128;
  const int mq0 = qb + w * 32;
  const float scale = 0.08838834764831845f;  // 1/sqrt(128)

  // Q fragments: A[m=l15][k=quad*8+j] per 32-chunk
  bf16x8 qa[2][4];
#pragma unroll
  for (int mi = 0; mi < 2; ++mi) {
    const u16* qp = qkv + (size_t)(mq0 + mi * 16 + l15) * NQKV + h * HDIM + quad * 8;
#pragma unroll
    for (int c = 0; c < 4; ++c) qa[mi][c] = *(const bf16x8*)(qp + c * 32);
  }

  floatx4 o[2][8];
#pragma unroll
  for (int mi = 0; mi < 2; ++mi)
#pragma unroll
    for (int nf = 0; nf < 8; ++nf)
#pragma unroll
      for (int j = 0; j < 4; ++j) o[mi][nf][j] = 0.0f;
  float mrow[2][4], lrow[2][4];
#pragma unroll
  for (int mi = 0; mi < 2; ++mi)
#pragma unroll
    for (int j = 0; j < 4; ++j) { mrow[mi][j] = -1e30f; lrow[mi][j] = 0.0f; }

  const int nkt = 2 * bx + 2;       // 64-key tiles covering keys <= qb+127
  const int srow = lane >> 2;       // 0..15
  const int scol = (lane & 3) * 8;  // element col offset
  const int kbase = D_DIM + hk * HDIM;

  for (int kt = 0; kt < nkt; ++kt) {
    const int kb = kt * 64;
    // ---- stage K tile: wave w stages keys w*16..w*16+15 of each 32-hd chunk
#pragma unroll
    for (int c = 0; c < 4; ++c)
      gll16(qkv + (size_t)(kb + w * 16 + srow) * NQKV + kbase + c * 32 + scol,
            &Ks[c][(w * 16) * 32]);
    // ---- stage V^T tile: wave w stages hd rows w*32..w*32+31 of each 32-key chunk
#pragma unroll
    for (int c = 0; c < 2; ++c)
#pragma unroll
      for (int i = 0; i < 2; ++i)
        gll16(vt + ((size_t)hk * HDIM + w * 32 + i * 16 + srow) * S_LEN + kb + c * 32 + scol,
              &Vs[c][(w * 32 + i * 16) * 32]);
    __syncthreads();

    if (kb <= mq0 + 31) {  // wave-uniform causal skip
#pragma unroll
      for (int mi = 0; mi < 2; ++mi) {
        floatx4 sn[4];
#pragma unroll
        for (int ni = 0; ni < 4; ++ni)
#pragma unroll
          for (int j = 0; j < 4; ++j) sn[ni][j] = 0.0f;
#pragma unroll
        for (int c = 0; c < 4; ++c) {
#pragma unroll
          for (int ni = 0; ni < 4; ++ni) {
            bf16x8 kf = *(const bf16x8*)(&Ks[c][(ni * 16 + l15) * 32 + quad * 8]);
            sn[ni] = __builtin_amdgcn_mfma_f32_16x16x32_bf16(qa[mi][c], kf, sn[ni], 0, 0, 0);
          }
        }
        const int rowg = mq0 + mi * 16 + quad * 4;
        float al[4];
#pragma unroll
        for (int j = 0; j < 4; ++j) {
          float v[4];
#pragma unroll
          for (int ni = 0; ni < 4; ++ni) {
            v[ni] = sn[ni][j] * scale;
            if (kb + ni * 16 + l15 > rowg + j) v[ni] = -1e30f;
          }
          float mj = fmaxf(fmaxf(v[0], v[1]), fmaxf(v[2], v[3]));
#pragma unroll
          for (int off = 1; off < 16; off <<= 1) mj = fmaxf(mj, __shfl_xor(mj, off, 64));
          float mn = fmaxf(mrow[mi][j], mj);
          float a_ = __expf(mrow[mi][j] - mn);
          mrow[mi][j] = mn;
          float ps = 0.0f;
#pragma unroll
          for (int ni = 0; ni < 4; ++ni) {
            float p = __expf(v[ni] - mn);
            ps += p;
            Ps[w][(quad * 4 + j) * 72 + ni * 16 + l15] = f2bf(p);
          }
#pragma unroll
          for (int off = 1; off < 16; off <<= 1) ps += __shfl_xor(ps, off, 64);
          lrow[mi][j] = lrow[mi][j] * a_ + ps;
          al[j] = a_;
        }
#pragma unroll
        for (int nf = 0; nf < 8; ++nf)
#pragma unroll
          for (int j = 0; j < 4; ++j) o[mi][nf][j] *= al[j];
        bf16x8 pa0 = *(const bf16x8*)(&Ps[w][l15 * 72 + quad * 8]);
        bf16x8 pa1 = *(const bf16x8*)(&Ps[w][l15 * 72 + 32 + quad * 8]);
#pragma unroll
        for (int nf = 0; nf < 8; ++nf) {
          bf16x8 vb0 = *(const bf16x8*)(&Vs[0][(nf * 16 + l15) * 32 + quad * 8]);
          bf16x8 vb1 = *(const bf16x8*)(&Vs[1][(nf * 16 + l15) * 32 + quad * 8]);
          o[mi][nf] = __builtin_amdgcn_mfma_f32_16x16x32_bf16(pa0, vb0, o[mi][nf], 0, 0, 0);
          o[mi][nf] = __builtin_amdgcn_mfma_f32_16x16x32_bf16(pa1, vb1, o[mi][nf], 0, 0, 0);
        }
      }
    }
    __syncthreads();
  }

#pragma unroll
  for (int mi = 0; mi < 2; ++mi) {
    float rl[4];
#pragma unroll
    for (int j = 0; j < 4; ++j) rl[j] = 1.0f / lrow[mi][j];
#pragma unroll
    for (int nf = 0; nf < 8; ++nf)
#pragma unroll
      for (int j = 0; j < 4; ++j) {
        int row = mq0 + mi * 16 + quad * 4 + j;
        int col = h * HDIM + nf * 16 + l15;
        attn_o[(size_t)row * D_DIM + col] = f2bf(o[mi][nf][j] * rl[j]);
      }
  }
}

// ---------------- launcher ----------------

extern "C" void kernel_launch(void* const* d_in, const int* in_sizes, int n_in,
                              void* d_out, int out_size, void* d_ws, size_t ws_size,
                              hipStream_t stream) {
  const float* x  = (const float*)d_in[0];
  const float* Wq = (const float*)d_in[1];
  const float* Wk = (const float*)d_in[2];
  const float* Wv = (const float*)d_in[3];
  const float* Wo = (const float*)d_in[4];
  float* out = (float*)d_out;
  char* ws = (char*)d_ws;
  const size_t MB = 1024 * 1024;
  u16* x_bf   = (u16*)(ws);              // 16 MB
  u16* wqkvT  = (u16*)(ws + 16 * MB);    // 48 MB  [6144][4096] bf16
  u16* woT    = (u16*)(ws + 64 * MB);    // 32 MB  [4096][4096] bf16
  u16* qkv    = (u16*)(ws + 96 * MB);    // 24 MB  [2048][6144] bf16
  u16* vt     = (u16*)(ws + 120 * MB);   //  4 MB  [8][128][2048] bf16
  u16* attn_o = (u16*)(ws + 124 * MB);   // 16 MB  [2048][4096] bf16

  cast_f32_bf16<<<8192, 256, 0, stream>>>(x, x_bf, S_LEN * D_DIM);
  transpose_cast<<<dim3(64, 64), 256, 0, stream>>>(Wq, wqkvT, D_DIM, 4096);
  transpose_cast<<<dim3(64, 16), 256, 0, stream>>>(Wk, wqkvT + (size_t)4096 * D_DIM, D_DIM, 1024);
  transpose_cast<<<dim3(64, 16), 256, 0, stream>>>(Wv, wqkvT + (size_t)5120 * D_DIM, D_DIM, 1024);
  transpose_cast<<<dim3(64, 64), 256, 0, stream>>>(Wo, woT, D_DIM, D_DIM);
  gemm_bt<true><<<dim3(48, 16), 256, 0, stream>>>(x_bf, wqkvT, qkv, S_LEN, NQKV, D_DIM);
  rope_kernel<<<dim3(S_LEN, 10), 256, 0, stream>>>(qkv);
  vt_kernel<<<dim3(32, 2, 8), 256, 0, stream>>>(qkv, vt);
  attn_kernel<<<dim3(S_LEN / 128, NHEAD), 256, 0, stream>>>(qkv, vt, attn_o);
  gemm_bt<false><<<dim3(32, 16), 256, 0, stream>>>(attn_o, woT, out, S_LEN, D_DIM, D_DIM);
}

// Round 3
// 585.688 us; speedup vs baseline: 1.5697x; 1.1146x over previous
//
#include <hip/hip_runtime.h>
#include <cstdint>

#define S_LEN 2048
#define D_DIM 4096
#define NHEAD 32
#define NKVH  8
#define HDIM  128
#define NQKV  6144

typedef __bf16 bf16x8 __attribute__((ext_vector_type(8)));
typedef float floatx4 __attribute__((ext_vector_type(4)));
typedef unsigned short u16;
typedef unsigned int u32;

__device__ __forceinline__ u16 f2bf(float f) {
  u32 u = __builtin_bit_cast(u32, f);
  u += 0x7fffu + ((u >> 16) & 1u);
  return (u16)(u >> 16);
}
__device__ __forceinline__ float bf2f(u16 h) {
  u32 u = ((u32)h) << 16;
  return __builtin_bit_cast(float, u);
}

// async global->LDS, 16B per lane; LDS dest = wave-uniform base + lane*16
__device__ __forceinline__ void gll16(const void* g, const void* l) {
  __builtin_amdgcn_global_load_lds(
      (const __attribute__((address_space(1))) u32*)(unsigned long long)(uintptr_t)g,
      (__attribute__((address_space(3))) u32*)(u32)(uintptr_t)l, 16, 0, 0);
}

// ---------------- prep kernels ----------------

__global__ __launch_bounds__(256) void cast_f32_bf16(const float* __restrict__ src,
                                                     u16* __restrict__ dst, int n) {
  int i = (blockIdx.x * 256 + threadIdx.x) * 4;
  if (i >= n) return;
  float4 v = *(const float4*)(src + i);
  u32 lo = (u32)f2bf(v.x) | ((u32)f2bf(v.y) << 16);
  u32 hi = (u32)f2bf(v.z) | ((u32)f2bf(v.w) << 16);
  *(uint2*)(dst + i) = make_uint2(lo, hi);
}

// src [K,N] f32 -> dst [N,K] bf16 (64x64 tiles)
__global__ __launch_bounds__(256) void transpose_cast(const float* __restrict__ src,
                                                      u16* __restrict__ dst, int K, int N) {
  __shared__ float tile[64][65];
  int k0 = blockIdx.x * 64, n0 = blockIdx.y * 64;
  int t = threadIdx.x, c = t & 63, r0 = t >> 6;
#pragma unroll
  for (int p = 0; p < 16; ++p) {
    int r = r0 + p * 4;
    tile[r][c] = src[(size_t)(k0 + r) * N + n0 + c];
  }
  __syncthreads();
#pragma unroll
  for (int p = 0; p < 16; ++p) {
    int rr = r0 + p * 4;  // n-local
    dst[(size_t)(n0 + rr) * K + k0 + c] = f2bf(tile[c][rr]);
  }
}

// extract V from qkv [S][6144] and transpose per kv-head -> vt [NKVH][HDIM][S]
__global__ __launch_bounds__(256) void vt_kernel(const u16* __restrict__ qkv,
                                                 u16* __restrict__ vt) {
  __shared__ u16 tile[64][65];
  int s0 = blockIdx.x * 64, d0 = blockIdx.y * 64, hk = blockIdx.z;
  int t = threadIdx.x, c = t & 63, r0 = t >> 6;
#pragma unroll
  for (int p = 0; p < 16; ++p) {
    int r = r0 + p * 4;  // s-local
    tile[r][c] = qkv[(size_t)(s0 + r) * NQKV + 5120 + hk * HDIM + d0 + c];
  }
  __syncthreads();
#pragma unroll
  for (int p = 0; p < 16; ++p) {
    int rr = r0 + p * 4;  // d-local
    vt[((size_t)hk * HDIM + d0 + rr) * S_LEN + s0 + c] = tile[c][rr];
  }
}

// in-place RoPE on q (heads 0..31) and k (heads 32..39) of qkv [S][6144]
__global__ __launch_bounds__(256) void rope_kernel(u16* __restrict__ qkv) {
  int s = blockIdx.x;
  int sub = threadIdx.x >> 6;
  int i = threadIdx.x & 63;  // pair index, dims (2i, 2i+1)
  int hh = blockIdx.y * 4 + sub;
  int colbase = (hh < NHEAD) ? hh * HDIM : D_DIM + (hh - NHEAD) * HDIM;
  u32* p = (u32*)(qkv + (size_t)s * NQKV + colbase) + i;
  u32 pr = *p;
  float x0 = bf2f((u16)(pr & 0xffffu));
  float x1 = bf2f((u16)(pr >> 16));
  float invf = expf(-(float)(2 * i) * (13.122363377404328f / 128.0f));
  float ang = (float)s * invf;
  float cs = cosf(ang), sn = sinf(ang);
  float o0 = x0 * cs - x1 * sn;
  float o1 = x0 * sn + x1 * cs;
  *p = (u32)f2bf(o0) | ((u32)f2bf(o1) << 16);
}

// ---------------- GEMM: C[M,N] = A[M,K] * Bt[N,K]^T ----------------

template <bool BF16_OUT>
__global__ __launch_bounds__(256) void gemm_bt(const u16* __restrict__ A,
                                               const u16* __restrict__ Bt,
                                               void* __restrict__ Cout,
                                               int M, int N, int K) {
  __shared__ u16 As[128 * 32];
  __shared__ u16 Bs[128 * 32];
  const int tid = threadIdx.x;
  const int w = tid >> 6, lane = tid & 63;
  const int quad = lane >> 4, l15 = lane & 15;
  const int m0 = blockIdx.y * 128, n0 = blockIdx.x * 128;
  const int wm = (w & 1) * 64, wn = (w >> 1) * 64;
  floatx4 acc[4][4];
#pragma unroll
  for (int mi = 0; mi < 4; ++mi)
#pragma unroll
    for (int ni = 0; ni < 4; ++ni)
#pragma unroll
      for (int j = 0; j < 4; ++j) acc[mi][ni][j] = 0.0f;

  const int srow = w * 32 + (lane >> 2);
  const int kcol = (lane & 3) * 8;

  for (int k0 = 0; k0 < K; k0 += 32) {
#pragma unroll
    for (int i = 0; i < 2; ++i) {
      gll16(A + (size_t)(m0 + srow + i * 16) * K + k0 + kcol,
            As + (w * 32 + i * 16) * 32);
      gll16(Bt + (size_t)(n0 + srow + i * 16) * K + k0 + kcol,
            Bs + (w * 32 + i * 16) * 32);
    }
    __syncthreads();
    bf16x8 a[4], b[4];
#pragma unroll
    for (int mi = 0; mi < 4; ++mi)
      a[mi] = *(const bf16x8*)(As + (wm + mi * 16 + l15) * 32 + quad * 8);
#pragma unroll
    for (int ni = 0; ni < 4; ++ni)
      b[ni] = *(const bf16x8*)(Bs + (wn + ni * 16 + l15) * 32 + quad * 8);
#pragma unroll
    for (int mi = 0; mi < 4; ++mi)
#pragma unroll
      for (int ni = 0; ni < 4; ++ni)
        acc[mi][ni] = __builtin_amdgcn_mfma_f32_16x16x32_bf16(a[mi], b[ni], acc[mi][ni], 0, 0, 0);
    __syncthreads();
  }
#pragma unroll
  for (int mi = 0; mi < 4; ++mi)
#pragma unroll
    for (int ni = 0; ni < 4; ++ni) {
      int row = m0 + wm + mi * 16 + quad * 4;
      int col = n0 + wn + ni * 16 + l15;
#pragma unroll
      for (int j = 0; j < 4; ++j) {
        if (BF16_OUT)
          ((u16*)Cout)[(size_t)(row + j) * N + col] = f2bf(acc[mi][ni][j]);
        else
          ((float*)Cout)[(size_t)(row + j) * N + col] = acc[mi][ni][j];
      }
    }
}

// ---------------- flash attention, transposed-score softmax ----------------
// grid (S/128, NHEAD); 4 waves, each owns 32 q rows (2 groups of 16).
// S^T = K*Q^T so each lane's 16 scores belong to one q-row (l15):
// row stats = in-register tree + 2 cross-quad shuffles (vs 16-lane reductions).
__global__ __launch_bounds__(256) void attn_kernel(const u16* __restrict__ qkv,
                                                   const u16* __restrict__ vt,
                                                   u16* __restrict__ attn_o) {
  __shared__ u16 Ks[4][64 * 32];   // [hd-chunk c][key][32 hd]    16 KB
  __shared__ u16 Vs[2][128 * 32];  // [key-chunk c2][hd][32 keys] 16 KB
  __shared__ u16 Ps[4][32 * 72];   // per-wave P [qrow 32][key 64, stride 72] 18 KB
  const int tid = threadIdx.x, w = tid >> 6, lane = tid & 63;
  const int quad = lane >> 4, l15 = lane & 15;
  const int h = blockIdx.y, hk = h >> 2;
  // alternate sweep direction per head half: pairs heavy(16-x) with light(x+1)
  const int bx = (h & 16) ? blockIdx.x : (gridDim.x - 1 - blockIdx.x);
  const int qb = bx * 128;
  const int mq0 = qb + w * 32;
  const float scale2 = 0.12751744591813488f;  // log2(e)/sqrt(128)

  // Q as B-operand: B[k=hd][n=qrow]; lane holds Q[mq0+g*16+l15][c*32+quad*8+j]
  bf16x8 qfrag[2][4];
#pragma unroll
  for (int g = 0; g < 2; ++g) {
    const u16* qp = qkv + (size_t)(mq0 + g * 16 + l15) * NQKV + h * HDIM + quad * 8;
#pragma unroll
    for (int c = 0; c < 4; ++c) qfrag[g][c] = *(const bf16x8*)(qp + c * 32);
  }

  floatx4 o[2][8];
#pragma unroll
  for (int g = 0; g < 2; ++g)
#pragma unroll
    for (int nf = 0; nf < 8; ++nf)
#pragma unroll
      for (int j = 0; j < 4; ++j) o[g][nf][j] = 0.0f;
  float m_[2] = {-1e30f, -1e30f}, l_[2] = {0.0f, 0.0f};

  const int nkt = 2 * bx + 2;
  const int srow = lane >> 2;       // 0..15
  const int scol = (lane & 3) * 8;  // element col offset
  const int kbase = D_DIM + hk * HDIM;

  for (int kt = 0; kt < nkt; ++kt) {
    const int kb = kt * 64;
    // stage K tile (64 keys x 128 hd) and V^T tile (128 hd x 64 keys)
#pragma unroll
    for (int c = 0; c < 4; ++c)
      gll16(qkv + (size_t)(kb + w * 16 + srow) * NQKV + kbase + c * 32 + scol,
            &Ks[c][(w * 16) * 32]);
#pragma unroll
    for (int c = 0; c < 2; ++c)
#pragma unroll
      for (int i = 0; i < 2; ++i)
        gll16(vt + ((size_t)hk * HDIM + w * 32 + i * 16 + srow) * S_LEN + kb + c * 32 + scol,
              &Vs[c][(w * 32 + i * 16) * 32]);
    __syncthreads();

    if (kb <= mq0) {  // wave-uniform causal skip (kb,mq0 both mult of 32)
      // ---- S^T: D[key][qrow] = K * Q^T
      floatx4 sn[2][4];
#pragma unroll
      for (int g = 0; g < 2; ++g)
#pragma unroll
        for (int ki = 0; ki < 4; ++ki)
#pragma unroll
          for (int j = 0; j < 4; ++j) sn[g][ki][j] = 0.0f;
#pragma unroll
      for (int c = 0; c < 4; ++c)
#pragma unroll
        for (int ki = 0; ki < 4; ++ki) {
          bf16x8 kf = *(const bf16x8*)(&Ks[c][(ki * 16 + l15) * 32 + quad * 8]);
          sn[0][ki] = __builtin_amdgcn_mfma_f32_16x16x32_bf16(kf, qfrag[0][c], sn[0][ki], 0, 0, 0);
          sn[1][ki] = __builtin_amdgcn_mfma_f32_16x16x32_bf16(kf, qfrag[1][c], sn[1][ki], 0, 0, 0);
        }
      // ---- per-q-row online softmax (lane-local row = l15)
      float alw[2];
#pragma unroll
      for (int g = 0; g < 2; ++g) {
        const int qrow = mq0 + g * 16 + l15;
        float v[16];
        float mv = -1e30f;
#pragma unroll
        for (int ki = 0; ki < 4; ++ki)
#pragma unroll
          for (int dj = 0; dj < 4; ++dj) {
            int key = kb + ki * 16 + quad * 4 + dj;
            float s = sn[g][ki][dj] * scale2;
            float vv = (key > qrow) ? -1e30f : s;
            v[ki * 4 + dj] = vv;
            mv = fmaxf(mv, vv);
          }
        mv = fmaxf(mv, __shfl_xor(mv, 16, 64));
        mv = fmaxf(mv, __shfl_xor(mv, 32, 64));
        float mn = fmaxf(m_[g], mv);
        float a_ = exp2f(m_[g] - mn);
        m_[g] = mn;
        float ps = 0.0f;
#pragma unroll
        for (int ki = 0; ki < 4; ++ki) {
          u32 pk0, pk1;
          {
            float p0 = exp2f(v[ki * 4 + 0] - mn);
            float p1 = exp2f(v[ki * 4 + 1] - mn);
            float p2 = exp2f(v[ki * 4 + 2] - mn);
            float p3 = exp2f(v[ki * 4 + 3] - mn);
            ps += (p0 + p1) + (p2 + p3);
            pk0 = (u32)f2bf(p0) | ((u32)f2bf(p1) << 16);
            pk1 = (u32)f2bf(p2) | ((u32)f2bf(p3) << 16);
          }
          *(uint2*)(&Ps[w][(g * 16 + l15) * 72 + ki * 16 + quad * 4]) = make_uint2(pk0, pk1);
        }
        ps += __shfl_xor(ps, 16, 64);
        ps += __shfl_xor(ps, 32, 64);
        l_[g] = l_[g] * a_ + ps;
        alw[g] = a_;
      }
      // ---- rescale O by alpha (per q-row, broadcast to C-layout rows)
#pragma unroll
      for (int g = 0; g < 2; ++g) {
        float al[4];
#pragma unroll
        for (int dj = 0; dj < 4; ++dj) al[dj] = __shfl(alw[g], quad * 4 + dj, 16);
#pragma unroll
        for (int nf = 0; nf < 8; ++nf)
#pragma unroll
          for (int dj = 0; dj < 4; ++dj) o[g][nf][dj] *= al[dj];
      }
      // ---- PV: O[qrow][hd] += P * V
      bf16x8 pa[2][2];
#pragma unroll
      for (int g = 0; g < 2; ++g)
#pragma unroll
        for (int c2 = 0; c2 < 2; ++c2)
          pa[g][c2] = *(const bf16x8*)(&Ps[w][(g * 16 + l15) * 72 + c2 * 32 + quad * 8]);
#pragma unroll
      for (int nf = 0; nf < 8; ++nf) {
        bf16x8 vb0 = *(const bf16x8*)(&Vs[0][(nf * 16 + l15) * 32 + quad * 8]);
        bf16x8 vb1 = *(const bf16x8*)(&Vs[1][(nf * 16 + l15) * 32 + quad * 8]);
#pragma unroll
        for (int g = 0; g < 2; ++g) {
          o[g][nf] = __builtin_amdgcn_mfma_f32_16x16x32_bf16(pa[g][0], vb0, o[g][nf], 0, 0, 0);
          o[g][nf] = __builtin_amdgcn_mfma_f32_16x16x32_bf16(pa[g][1], vb1, o[g][nf], 0, 0, 0);
        }
      }
    }
    __syncthreads();
  }

  // ---- epilogue
#pragma unroll
  for (int g = 0; g < 2; ++g) {
    float linv = 1.0f / l_[g];
    float rl[4];
#pragma unroll
    for (int dj = 0; dj < 4; ++dj) rl[dj] = __shfl(linv, quad * 4 + dj, 16);
#pragma unroll
    for (int nf = 0; nf < 8; ++nf)
#pragma unroll
      for (int dj = 0; dj < 4; ++dj) {
        int row = mq0 + g * 16 + quad * 4 + dj;
        int col = h * HDIM + nf * 16 + l15;
        attn_o[(size_t)row * D_DIM + col] = f2bf(o[g][nf][dj] * rl[dj]);
      }
  }
}

// ---------------- launcher ----------------

extern "C" void kernel_launch(void* const* d_in, const int* in_sizes, int n_in,
                              void* d_out, int out_size, void* d_ws, size_t ws_size,
                              hipStream_t stream) {
  const float* x  = (const float*)d_in[0];
  const float* Wq = (const float*)d_in[1];
  const float* Wk = (const float*)d_in[2];
  const float* Wv = (const float*)d_in[3];
  const float* Wo = (const float*)d_in[4];
  float* out = (float*)d_out;
  char* ws = (char*)d_ws;
  const size_t MB = 1024 * 1024;
  u16* x_bf   = (u16*)(ws);              // 16 MB
  u16* wqkvT  = (u16*)(ws + 16 * MB);    // 48 MB  [6144][4096] bf16
  u16* woT    = (u16*)(ws + 64 * MB);    // 32 MB  [4096][4096] bf16
  u16* qkv    = (u16*)(ws + 96 * MB);    // 24 MB  [2048][6144] bf16
  u16* vt     = (u16*)(ws + 120 * MB);   //  4 MB  [8][128][2048] bf16
  u16* attn_o = (u16*)(ws + 124 * MB);   // 16 MB  [2048][4096] bf16

  cast_f32_bf16<<<8192, 256, 0, stream>>>(x, x_bf, S_LEN * D_DIM);
  transpose_cast<<<dim3(64, 64), 256, 0, stream>>>(Wq, wqkvT, D_DIM, 4096);
  transpose_cast<<<dim3(64, 16), 256, 0, stream>>>(Wk, wqkvT + (size_t)4096 * D_DIM, D_DIM, 1024);
  transpose_cast<<<dim3(64, 16), 256, 0, stream>>>(Wv, wqkvT + (size_t)5120 * D_DIM, D_DIM, 1024);
  transpose_cast<<<dim3(64, 64), 256, 0, stream>>>(Wo, woT, D_DIM, D_DIM);
  gemm_bt<true><<<dim3(48, 16), 256, 0, stream>>>(x_bf, wqkvT, qkv, S_LEN, NQKV, D_DIM);
  rope_kernel<<<dim3(S_LEN, 10), 256, 0, stream>>>(qkv);
  vt_kernel<<<dim3(32, 2, 8), 256, 0, stream>>>(qkv, vt);
  attn_kernel<<<dim3(S_LEN / 128, NHEAD), 256, 0, stream>>>(qkv, vt, attn_o);
  gemm_bt<false><<<dim3(32, 16), 256, 0, stream>>>(attn_o, woT, out, S_LEN, D_DIM, D_DIM);
}